// Round 8
// baseline (268.250 us; speedup 1.0000x reference)
//
#include <hip/hip_runtime.h>
#include <math.h>

// IdealScore: B=16, N=10000, D=3072, fp32.
//   arg[b][n] = (at/bt2)*dot(x_b, img_n) - ((1-sval)/(2*sval))*||img_n||^2
//   (x_sq dropped: softmax shift-invariant); w = softmax_n(arg);
//   out = (at*(w@imgs) - x)/bt2.  Near-one-hot softmax -> sparse pass 2.
//
// R8: k1 owns 4 rows x FULL D per wave, accumulating per-lane partials
// across all 12 chunks and reducing ONCE per wave (R6/R7 reduced per
// chunk: ~50% of VALU was shuffle overhead). pd intermediate gone --
// k1 writes final args (640 KB). Reduction macro is the R6-verified
// sequence, applied per row-pair.
#define BB 16
#define NN 10000
#define DD 3072
#define SEL_CUT 40.0f
#define CAP 1024         // selection capacity per batch row

// verified reduce-scatter step (R6) on float2 accumulator array `arr`
#define RSTEP2(arr, mm, cc)                                             \
  {                                                                     \
    const bool up = (lane & (mm)) != 0;                                 \
    _Pragma("unroll")                                                   \
    for (int k = 0; k < (cc); ++k) {                                    \
      float2 lo = arr[k], hi = arr[k + (cc)];                           \
      float sx = up ? lo.x : hi.x, sy = up ? lo.y : hi.y;               \
      float rx = __shfl_xor(sx, (mm), 64);                              \
      float ry = __shfl_xor(sy, (mm), 64);                              \
      arr[k].x = (up ? hi.x : lo.x) + rx;                               \
      arr[k].y = (up ? hi.y : lo.y) + ry;                               \
    }                                                                   \
  }
// full verified chain: after this, all 4 lanes of group (lane>>2) hold in
// arr[0] the FULL 64-lane sum for b=(lane>>2)&15 (.x=even row, .y=odd row)
#define RFULL(arr)                                                      \
  RSTEP2(arr, 32, 8)                                                    \
  RSTEP2(arr, 16, 4)                                                    \
  RSTEP2(arr, 8, 2)                                                     \
  RSTEP2(arr, 4, 1)                                                     \
  arr[0].x += __shfl_xor(arr[0].x, 2, 64);                              \
  arr[0].y += __shfl_xor(arr[0].y, 2, 64);                              \
  arr[0].x += __shfl_xor(arr[0].x, 1, 64);                              \
  arr[0].y += __shfl_xor(arr[0].y, 1, 64);

// ---- K1: args[b][n] = c1*dot(x_b,img_n) - c2*||img_n||^2 ----
// grid 625 x 256 thr (4 waves). Wave owns rows n0..n0+3 (2 pairs) x all D.
// Per chunk: 4 image float4 (prefetch depth 1) + 16 x float4 (L1-hot),
// 256 FMA into 64 persistent accumulator floats. One reduction per wave.
__global__ __launch_bounds__(256) void k1_args(
    const float* __restrict__ x, const float* __restrict__ images,
    const float* __restrict__ svalp, float* __restrict__ args)
{
  const int t = threadIdx.x;
  const int lane = t & 63;
  const int wave = t >> 6;
  const int n0 = (blockIdx.x * 4 + wave) * 4;   // 2500 waves * 4 = 10000 exact
  const int dl = lane << 2;                     // lane's float4 offset in chunk

  const float* __restrict__ r0 = images + (size_t)(n0 + 0) * DD;
  const float* __restrict__ r1 = images + (size_t)(n0 + 1) * DD;
  const float* __restrict__ r2 = images + (size_t)(n0 + 2) * DD;
  const float* __restrict__ r3 = images + (size_t)(n0 + 3) * DD;

  float2 acc0[BB], acc1[BB];                   // pair0 = rows 0/1, pair1 = 2/3
  float2 isq0 = make_float2(0.f, 0.f), isq1 = make_float2(0.f, 0.f);
#pragma unroll
  for (int b = 0; b < BB; ++b) {
    acc0[b] = make_float2(0.f, 0.f);
    acc1[b] = make_float2(0.f, 0.f);
  }

  float4 c0 = *(const float4*)&r0[dl];
  float4 c1 = *(const float4*)&r1[dl];
  float4 c2 = *(const float4*)&r2[dl];
  float4 c3 = *(const float4*)&r3[dl];

#pragma unroll 1
  for (int c = 0; c < 12; ++c) {
    float4 A0 = c0, A1 = c1, A2 = c2, A3 = c3;
    if (c != 11) {                             // uniform: prefetch next chunk
      const int dn = (c + 1) * 256 + dl;
      c0 = *(const float4*)&r0[dn];
      c1 = *(const float4*)&r1[dn];
      c2 = *(const float4*)&r2[dn];
      c3 = *(const float4*)&r3[dn];
    }

    isq0.x += A0.x * A0.x + A0.y * A0.y + A0.z * A0.z + A0.w * A0.w;
    isq0.y += A1.x * A1.x + A1.y * A1.y + A1.z * A1.z + A1.w * A1.w;
    isq1.x += A2.x * A2.x + A2.y * A2.y + A2.z * A2.z + A2.w * A2.w;
    isq1.y += A3.x * A3.x + A3.y * A3.y + A3.z * A3.z + A3.w * A3.w;

    const int dg = c * 256 + dl;
#pragma unroll
    for (int b = 0; b < BB; ++b) {
      float4 xv = *(const float4*)&x[b * DD + dg];   // L1-hot
      acc0[b].x += A0.x * xv.x + A0.y * xv.y + A0.z * xv.z + A0.w * xv.w;
      acc0[b].y += A1.x * xv.x + A1.y * xv.y + A1.z * xv.z + A1.w * xv.w;
      acc1[b].x += A2.x * xv.x + A2.y * xv.y + A2.z * xv.z + A2.w * xv.w;
      acc1[b].y += A3.x * xv.x + A3.y * xv.y + A3.z * xv.z + A3.w * xv.w;
    }
  }

  // one reduction per wave (verified R6 sequence, applied per pair)
  RFULL(acc0)
  RFULL(acc1)
#pragma unroll
  for (int m = 32; m >= 1; m >>= 1) {
    isq0.x += __shfl_xor(isq0.x, m, 64);
    isq0.y += __shfl_xor(isq0.y, m, 64);
    isq1.x += __shfl_xor(isq1.x, m, 64);
    isq1.y += __shfl_xor(isq1.y, m, 64);
  }

  const float sval = *svalp;
  const float at = sqrtf(1.f - sval);
  const float k1c = at / sval;                    // at / bt2
  const float k2c = (1.f - sval) / (2.f * sval);  // at^2 / (2*bt2)

  const int r = lane & 1;
  const int bb = (lane >> 2) & 15;
  if ((lane & 2) == 0) {
    // pair 0: rows n0, n0+1
    float d0 = r ? acc0[0].y : acc0[0].x;
    float s0 = r ? isq0.y    : isq0.x;
    args[bb * NN + (n0 + r)] = k1c * d0 - k2c * s0;
    // pair 1: rows n0+2, n0+3
    float d1 = r ? acc1[0].y : acc1[0].x;
    float s1 = r ? isq1.y    : isq1.x;
    args[bb * NN + (n0 + 2 + r)] = k1c * d1 - k2c * s1;
  }
}

// ---- K2: stats + select from args ----
// 16 blocks x 1024 thr; thread t owns n = t, t+1024, ... (<=10 values).
__global__ __launch_bounds__(1024) void k2_select(
    const float* __restrict__ args, int* __restrict__ cnt,
    int* __restrict__ idx, float* __restrict__ wv)
{
  __shared__ float red[16];
  __shared__ float mshared, lshared;
  const int b = blockIdx.x;
  const int t = threadIdx.x;
  const int lane = t & 63, wave = t >> 6;
  if (t == 0) cnt[b] = 0;                    // ws is poisoned 0xAA

  float a[10];
#pragma unroll
  for (int i = 0; i < 10; ++i) {
    int n = t + (i << 10);
    a[i] = (n < NN) ? args[b * NN + n] : -INFINITY;
  }

  float mx = -INFINITY;
#pragma unroll
  for (int i = 0; i < 10; ++i) mx = fmaxf(mx, a[i]);
#pragma unroll
  for (int m = 32; m >= 1; m >>= 1) mx = fmaxf(mx, __shfl_xor(mx, m, 64));
  if (lane == 0) red[wave] = mx;
  __syncthreads();
  if (wave == 0) {
    float v = (lane < 16) ? red[lane] : -INFINITY;
#pragma unroll
    for (int m = 8; m >= 1; m >>= 1) v = fmaxf(v, __shfl_xor(v, m, 64));
    if (lane == 0) mshared = v;
  }
  __syncthreads();
  mx = mshared;

  float s = 0.f;
#pragma unroll
  for (int i = 0; i < 10; ++i) s += __expf(a[i] - mx);  // exp(-inf)=0
#pragma unroll
  for (int m = 32; m >= 1; m >>= 1) s += __shfl_xor(s, m, 64);
  if (lane == 0) red[wave] = s;
  __syncthreads();
  if (wave == 0) {
    float v = (lane < 16) ? red[lane] : 0.f;
#pragma unroll
    for (int m = 8; m >= 1; m >>= 1) v += __shfl_xor(v, m, 64);
    if (lane == 0) lshared = v;
  }
  __syncthreads();
  const float invl = 1.f / lshared;

#pragma unroll
  for (int i = 0; i < 10; ++i) {
    if (a[i] > mx - SEL_CUT) {               // ~1-5 hits per row
      int k = atomicAdd(&cnt[b], 1);
      if (k < CAP) {
        idx[b * CAP + k] = t + (i << 10);
        wv[b * CAP + k] = __expf(a[i] - mx) * invl;
      }
    }
  }
}

// ---- K3: sparse mix + fused final affine -> out ----
__global__ __launch_bounds__(256) void k3_sparse(
    const float* __restrict__ images, const float* __restrict__ x,
    const float* __restrict__ svalp, const int* __restrict__ cnt,
    const int* __restrict__ idx, const float* __restrict__ wv,
    float* __restrict__ out)
{
  const int b = blockIdx.y;
  const int d0 = blockIdx.x * 1024 + (threadIdx.x << 2);
  int c = cnt[b];
  if (c > CAP) c = CAP;

  float4 acc = make_float4(0.f, 0.f, 0.f, 0.f);
  for (int j = 0; j < c; ++j) {
    int n = idx[b * CAP + j];
    float w = wv[b * CAP + j];
    float4 im = *(const float4*)&images[(size_t)n * DD + d0];
    acc.x += w * im.x; acc.y += w * im.y;
    acc.z += w * im.z; acc.w += w * im.w;
  }

  const float sval = *svalp;
  const float at = sqrtf(1.f - sval);
  const float inv_bt2 = 1.f / sval;
  float4 xv = *(const float4*)&x[b * DD + d0];
  float4 o;
  o.x = (at * acc.x - xv.x) * inv_bt2;
  o.y = (at * acc.y - xv.y) * inv_bt2;
  o.z = (at * acc.z - xv.z) * inv_bt2;
  o.w = (at * acc.w - xv.w) * inv_bt2;
  *(float4*)&out[b * DD + d0] = o;
}

extern "C" void kernel_launch(void* const* d_in, const int* in_sizes, int n_in,
                              void* d_out, int out_size, void* d_ws, size_t ws_size,
                              hipStream_t stream) {
  const float* x      = (const float*)d_in[0];
  const float* images = (const float*)d_in[1];
  const float* sval   = (const float*)d_in[2];
  float* out = (float*)d_out;
  float* ws  = (float*)d_ws;

  // ws layout (floats): args[16*10000] | cnt[16]i | pad[16] |
  //                     idx[16*1024]i | wv[16*1024]   -> 771 KB
  float* args = ws;
  int*   cnt  = (int*)(ws + 160000);
  int*   idx  = (int*)(ws + 160032);
  float* wv   = ws + 176416;

  hipLaunchKernelGGL(k1_args, dim3(625), dim3(256), 0, stream,
                     x, images, sval, args);
  hipLaunchKernelGGL(k2_select, dim3(16), dim3(1024), 0, stream,
                     args, cnt, idx, wv);
  hipLaunchKernelGGL(k3_sparse, dim3(3, 16), dim3(256), 0, stream,
                     images, x, sval, cnt, idx, wv, out);
}

// Round 9
// 198.300 us; speedup vs baseline: 1.3527x; 1.3527x over previous
//
#include <hip/hip_runtime.h>
#include <math.h>

// IdealScore: B=16, N=10000, D=3072, fp32.
//   arg[b][n] = (at/bt2)*dot(x_b, img_n) - ((1-sval)/(2*sval))*||img_n||^2
//   (x_sq dropped: softmax shift-invariant); w = softmax_n(arg);
//   out = (at*(w@imgs) - x)/bt2.  Near-one-hot softmax -> sparse pass 2.
//
// R9 = R8 (full-D rows, ONE reduction/wave — reduction overhead 8%) with
// the x operand moved to double-buffered LDS staged by global_load_lds DMA.
// R8's counters (VGPR=64 = accumulators only, VALU 11%) proved the
// allocator strips register prefetch when 64 acc floats are live; the DMA
// has no dest VGPR so it cannot be sunk, and x reads become ds_read_b128.
// One barrier/chunk: buf[(c+1)&1] written after barrier c, read after
// barrier c+1 (RAW and WAR each span exactly one barrier).
#define BB 16
#define NN 10000
#define DD 3072
#define SEL_CUT 40.0f
#define CAP 1024         // selection capacity per batch row

typedef const float __attribute__((address_space(1)))* gas_t;
typedef float __attribute__((address_space(3)))* las_t;

// verified reduce-scatter step (R6/R8) on float2 accumulator array `arr`
#define RSTEP2(arr, mm, cc)                                             \
  {                                                                     \
    const bool up = (lane & (mm)) != 0;                                 \
    _Pragma("unroll")                                                   \
    for (int k = 0; k < (cc); ++k) {                                    \
      float2 lo = arr[k], hi = arr[k + (cc)];                           \
      float sx = up ? lo.x : hi.x, sy = up ? lo.y : hi.y;               \
      float rx = __shfl_xor(sx, (mm), 64);                              \
      float ry = __shfl_xor(sy, (mm), 64);                              \
      arr[k].x = (up ? hi.x : lo.x) + rx;                               \
      arr[k].y = (up ? hi.y : lo.y) + ry;                               \
    }                                                                   \
  }
// after RFULL, all 4 lanes of group (lane>>2) hold in arr[0] the FULL
// 64-lane sum for b=(lane>>2)&15 (.x = even row, .y = odd row)
#define RFULL(arr)                                                      \
  RSTEP2(arr, 32, 8)                                                    \
  RSTEP2(arr, 16, 4)                                                    \
  RSTEP2(arr, 8, 2)                                                     \
  RSTEP2(arr, 4, 1)                                                     \
  arr[0].x += __shfl_xor(arr[0].x, 2, 64);                              \
  arr[0].y += __shfl_xor(arr[0].y, 2, 64);                              \
  arr[0].x += __shfl_xor(arr[0].x, 1, 64);                              \
  arr[0].y += __shfl_xor(arr[0].y, 1, 64);

// ---- K1: args[b][n] = c1*dot(x_b,img_n) - c2*||img_n||^2 ----
// grid 625 x 256 thr (4 waves). Wave owns rows n0..n0+3 x full D.
// Per 256-float chunk: 4 DMA stages (next x chunk), 4 rolling image
// loads, 16 ds_read_b128 (x), 256+16 FMA. One __syncthreads per chunk.
__global__ __launch_bounds__(256) void k1_args(
    const float* __restrict__ x, const float* __restrict__ images,
    const float* __restrict__ svalp, float* __restrict__ args)
{
  __shared__ float xs[2][BB * 256];            // 32 KB double buffer
  const int t = threadIdx.x;
  const int lane = t & 63;
  const int wave = t >> 6;
  const int n0 = (blockIdx.x * 4 + wave) * 4;  // 2500 waves * 4 = 10000 exact
  const int dl = lane << 2;

  const float* __restrict__ r0 = images + (size_t)(n0 + 0) * DD;
  const float* __restrict__ r1 = images + (size_t)(n0 + 1) * DD;
  const float* __restrict__ r2 = images + (size_t)(n0 + 2) * DD;
  const float* __restrict__ r3 = images + (size_t)(n0 + 3) * DD;

  float2 acc0[BB], acc1[BB];                   // pair0 = rows 0/1, pair1 = 2/3
  float2 isq0 = make_float2(0.f, 0.f), isq1 = make_float2(0.f, 0.f);
#pragma unroll
  for (int b = 0; b < BB; ++b) {
    acc0[b] = make_float2(0.f, 0.f);
    acc1[b] = make_float2(0.f, 0.f);
  }

  // prologue: DMA-stage x chunk 0 into buf 0 (wave w stages b=4w..4w+3;
  // LDS dest = uniform base + lane*16, global src contiguous per lane)
#pragma unroll
  for (int i = 0; i < 4; ++i) {
    const int b = wave * 4 + i;
    __builtin_amdgcn_global_load_lds((gas_t)(x + b * DD + dl),
                                     (las_t)(&xs[0][b * 256]), 16, 0, 0);
  }

  // rolling image prefetch (chunk 0)
  float4 c0 = *(const float4*)&r0[dl];
  float4 c1 = *(const float4*)&r1[dl];
  float4 c2 = *(const float4*)&r2[dl];
  float4 c3 = *(const float4*)&r3[dl];

#pragma unroll 1
  for (int c = 0; c < 12; ++c) {
    __syncthreads();                           // drains DMA for buf[c&1]

    if (c < 11) {                              // DMA-stage chunk c+1
      const int dn = (c + 1) * 256;
#pragma unroll
      for (int i = 0; i < 4; ++i) {
        const int b = wave * 4 + i;
        __builtin_amdgcn_global_load_lds((gas_t)(x + b * DD + dn + dl),
                                         (las_t)(&xs[(c + 1) & 1][b * 256]),
                                         16, 0, 0);
      }
    }

    float4 A0 = c0, A1 = c1, A2 = c2, A3 = c3;
    if (c < 11) {                              // roll image prefetch
      const int dn = (c + 1) * 256 + dl;
      c0 = *(const float4*)&r0[dn];
      c1 = *(const float4*)&r1[dn];
      c2 = *(const float4*)&r2[dn];
      c3 = *(const float4*)&r3[dn];
    }

    isq0.x += A0.x * A0.x + A0.y * A0.y + A0.z * A0.z + A0.w * A0.w;
    isq0.y += A1.x * A1.x + A1.y * A1.y + A1.z * A1.z + A1.w * A1.w;
    isq1.x += A2.x * A2.x + A2.y * A2.y + A2.z * A2.z + A2.w * A2.w;
    isq1.y += A3.x * A3.x + A3.y * A3.y + A3.z * A3.z + A3.w * A3.w;

    const float* xb = &xs[c & 1][dl];
#pragma unroll
    for (int b = 0; b < BB; ++b) {
      float4 xv = *(const float4*)&xb[b * 256]; // ds_read_b128, conflict-free
      acc0[b].x += A0.x * xv.x + A0.y * xv.y + A0.z * xv.z + A0.w * xv.w;
      acc0[b].y += A1.x * xv.x + A1.y * xv.y + A1.z * xv.z + A1.w * xv.w;
      acc1[b].x += A2.x * xv.x + A2.y * xv.y + A2.z * xv.z + A2.w * xv.w;
      acc1[b].y += A3.x * xv.x + A3.y * xv.y + A3.z * xv.z + A3.w * xv.w;
    }
  }

  // one reduction per wave (verified R6/R8 sequence)
  RFULL(acc0)
  RFULL(acc1)
#pragma unroll
  for (int m = 32; m >= 1; m >>= 1) {
    isq0.x += __shfl_xor(isq0.x, m, 64);
    isq0.y += __shfl_xor(isq0.y, m, 64);
    isq1.x += __shfl_xor(isq1.x, m, 64);
    isq1.y += __shfl_xor(isq1.y, m, 64);
  }

  const float sval = *svalp;
  const float at = sqrtf(1.f - sval);
  const float k1c = at / sval;                    // at / bt2
  const float k2c = (1.f - sval) / (2.f * sval);  // at^2 / (2*bt2)

  const int r = lane & 1;
  const int bb = (lane >> 2) & 15;
  if ((lane & 2) == 0) {
    float d0 = r ? acc0[0].y : acc0[0].x;
    float s0 = r ? isq0.y    : isq0.x;
    args[bb * NN + (n0 + r)] = k1c * d0 - k2c * s0;
    float d1 = r ? acc1[0].y : acc1[0].x;
    float s1 = r ? isq1.y    : isq1.x;
    args[bb * NN + (n0 + 2 + r)] = k1c * d1 - k2c * s1;
  }
}

// ---- K2: stats + select from args ----
__global__ __launch_bounds__(1024) void k2_select(
    const float* __restrict__ args, int* __restrict__ cnt,
    int* __restrict__ idx, float* __restrict__ wv)
{
  __shared__ float red[16];
  __shared__ float mshared, lshared;
  const int b = blockIdx.x;
  const int t = threadIdx.x;
  const int lane = t & 63, wave = t >> 6;
  if (t == 0) cnt[b] = 0;                    // ws is poisoned 0xAA

  float a[10];
#pragma unroll
  for (int i = 0; i < 10; ++i) {
    int n = t + (i << 10);
    a[i] = (n < NN) ? args[b * NN + n] : -INFINITY;
  }

  float mx = -INFINITY;
#pragma unroll
  for (int i = 0; i < 10; ++i) mx = fmaxf(mx, a[i]);
#pragma unroll
  for (int m = 32; m >= 1; m >>= 1) mx = fmaxf(mx, __shfl_xor(mx, m, 64));
  if (lane == 0) red[wave] = mx;
  __syncthreads();
  if (wave == 0) {
    float v = (lane < 16) ? red[lane] : -INFINITY;
#pragma unroll
    for (int m = 8; m >= 1; m >>= 1) v = fmaxf(v, __shfl_xor(v, m, 64));
    if (lane == 0) mshared = v;
  }
  __syncthreads();
  mx = mshared;

  float s = 0.f;
#pragma unroll
  for (int i = 0; i < 10; ++i) s += __expf(a[i] - mx);  // exp(-inf)=0
#pragma unroll
  for (int m = 32; m >= 1; m >>= 1) s += __shfl_xor(s, m, 64);
  if (lane == 0) red[wave] = s;
  __syncthreads();
  if (wave == 0) {
    float v = (lane < 16) ? red[lane] : 0.f;
#pragma unroll
    for (int m = 8; m >= 1; m >>= 1) v += __shfl_xor(v, m, 64);
    if (lane == 0) lshared = v;
  }
  __syncthreads();
  const float invl = 1.f / lshared;

#pragma unroll
  for (int i = 0; i < 10; ++i) {
    if (a[i] > mx - SEL_CUT) {               // ~1-5 hits per row
      int k = atomicAdd(&cnt[b], 1);
      if (k < CAP) {
        idx[b * CAP + k] = t + (i << 10);
        wv[b * CAP + k] = __expf(a[i] - mx) * invl;
      }
    }
  }
}

// ---- K3: sparse mix + fused final affine -> out ----
__global__ __launch_bounds__(256) void k3_sparse(
    const float* __restrict__ images, const float* __restrict__ x,
    const float* __restrict__ svalp, const int* __restrict__ cnt,
    const int* __restrict__ idx, const float* __restrict__ wv,
    float* __restrict__ out)
{
  const int b = blockIdx.y;
  const int d0 = blockIdx.x * 1024 + (threadIdx.x << 2);
  int c = cnt[b];
  if (c > CAP) c = CAP;

  float4 acc = make_float4(0.f, 0.f, 0.f, 0.f);
  for (int j = 0; j < c; ++j) {
    int n = idx[b * CAP + j];
    float w = wv[b * CAP + j];
    float4 im = *(const float4*)&images[(size_t)n * DD + d0];
    acc.x += w * im.x; acc.y += w * im.y;
    acc.z += w * im.z; acc.w += w * im.w;
  }

  const float sval = *svalp;
  const float at = sqrtf(1.f - sval);
  const float inv_bt2 = 1.f / sval;
  float4 xv = *(const float4*)&x[b * DD + d0];
  float4 o;
  o.x = (at * acc.x - xv.x) * inv_bt2;
  o.y = (at * acc.y - xv.y) * inv_bt2;
  o.z = (at * acc.z - xv.z) * inv_bt2;
  o.w = (at * acc.w - xv.w) * inv_bt2;
  *(float4*)&out[b * DD + d0] = o;
}

extern "C" void kernel_launch(void* const* d_in, const int* in_sizes, int n_in,
                              void* d_out, int out_size, void* d_ws, size_t ws_size,
                              hipStream_t stream) {
  const float* x      = (const float*)d_in[0];
  const float* images = (const float*)d_in[1];
  const float* sval   = (const float*)d_in[2];
  float* out = (float*)d_out;
  float* ws  = (float*)d_ws;

  // ws layout (floats): args[16*10000] | cnt[16]i | pad[16] |
  //                     idx[16*1024]i | wv[16*1024]   -> 771 KB
  float* args = ws;
  int*   cnt  = (int*)(ws + 160000);
  int*   idx  = (int*)(ws + 160032);
  float* wv   = ws + 176416;

  hipLaunchKernelGGL(k1_args, dim3(625), dim3(256), 0, stream,
                     x, images, sval, args);
  hipLaunchKernelGGL(k2_select, dim3(16), dim3(1024), 0, stream,
                     args, cnt, idx, wv);
  hipLaunchKernelGGL(k3_sparse, dim3(3, 16), dim3(256), 0, stream,
                     images, x, sval, cnt, idx, wv, out);
}

// Round 10
// 197.603 us; speedup vs baseline: 1.3575x; 1.0035x over previous
//
#include <hip/hip_runtime.h>
#include <math.h>

// IdealScore: B=16, N=10000, D=3072, fp32.
//   arg[b][n] = (at/bt2)*dot(x_b, img_n) - ((1-sval)/(2*sval))*||img_n||^2
//   (x_sq dropped: softmax shift-invariant); w = softmax_n(arg);
//   out = (at*(w@imgs) - x)/bt2.  Near-one-hot softmax -> sparse pass 2.
//
// R10 = R9's LDS-DMA trick (allocator can't sink a dest-less DMA; x reads
// are ds_read_b128) restructured to remove ALL in-loop barriers: block =
// (n-group, d-quarter), stages its 48 KB x quarter-slice ONCE, one
// __syncthreads, then a barrier-free 3-chunk loop. Grid 625->2500 blocks
// (R9 was residency-bound: 2.44 waves/SIMD + 12 barrier drains/block).
#define BB 16
#define NN 10000
#define DD 3072
#define DQ 768           // d-quarter
#define SEL_CUT 40.0f
#define CAP 1024         // selection capacity per batch row

typedef const float __attribute__((address_space(1)))* gas_t;
typedef float __attribute__((address_space(3)))* las_t;

// verified reduce-scatter step (R6/R8/R9) on float2 accumulator array
#define RSTEP2(arr, mm, cc)                                             \
  {                                                                     \
    const bool up = (lane & (mm)) != 0;                                 \
    _Pragma("unroll")                                                   \
    for (int k = 0; k < (cc); ++k) {                                    \
      float2 lo = arr[k], hi = arr[k + (cc)];                           \
      float sx = up ? lo.x : hi.x, sy = up ? lo.y : hi.y;               \
      float rx = __shfl_xor(sx, (mm), 64);                              \
      float ry = __shfl_xor(sy, (mm), 64);                              \
      arr[k].x = (up ? hi.x : lo.x) + rx;                               \
      arr[k].y = (up ? hi.y : lo.y) + ry;                               \
    }                                                                   \
  }
// after RFULL, all 4 lanes of group (lane>>2) hold in arr[0] the FULL
// 64-lane sum for b=(lane>>2)&15 (.x = even row, .y = odd row)
#define RFULL(arr)                                                      \
  RSTEP2(arr, 32, 8)                                                    \
  RSTEP2(arr, 16, 4)                                                    \
  RSTEP2(arr, 8, 2)                                                     \
  RSTEP2(arr, 4, 1)                                                     \
  arr[0].x += __shfl_xor(arr[0].x, 2, 64);                              \
  arr[0].y += __shfl_xor(arr[0].y, 2, 64);                              \
  arr[0].x += __shfl_xor(arr[0].x, 1, 64);                              \
  arr[0].y += __shfl_xor(arr[0].y, 1, 64);

// ---- K1: pd[q][b][n] = c1*dot_q(x_b,img_n) - c2*isq_q(n) ----
// grid (625, 4) x 256 thr (4 waves). Wave owns rows n0..n0+3 x one
// d-quarter (3 chunks of 256 floats). x quarter-slice staged once in LDS.
__global__ __launch_bounds__(256) void k1_partial(
    const float* __restrict__ x, const float* __restrict__ images,
    const float* __restrict__ svalp, float* __restrict__ pd)
{
  __shared__ float xs[BB * DQ];                // 48 KB, single buffer
  const int t = threadIdx.x;
  const int lane = t & 63;
  const int wave = t >> 6;
  const int q = blockIdx.y;
  const int qb = q * DQ;
  const int n0 = (blockIdx.x * 4 + wave) * 4;  // 2500 waves * 4 = 10000 exact
  const int dl = lane << 2;

  // stage x[:, qb..qb+767] once: wave w stages b = 4w..4w+3, 3 chunks each.
  // LDS dest = wave-uniform base + lane*16 (DMA constraint, m104/m108).
#pragma unroll
  for (int i = 0; i < 4; ++i) {
    const int b = wave * 4 + i;
#pragma unroll
    for (int cc = 0; cc < 3; ++cc) {
      __builtin_amdgcn_global_load_lds(
          (gas_t)(x + b * DD + qb + cc * 256 + dl),
          (las_t)(&xs[b * DQ + cc * 256]), 16, 0, 0);
    }
  }

  const float* __restrict__ r0 = images + (size_t)(n0 + 0) * DD + qb;
  const float* __restrict__ r1 = images + (size_t)(n0 + 1) * DD + qb;
  const float* __restrict__ r2 = images + (size_t)(n0 + 2) * DD + qb;
  const float* __restrict__ r3 = images + (size_t)(n0 + 3) * DD + qb;

  // image chunk-0 prefetch rides in front of the barrier's vmcnt drain
  float4 c0 = *(const float4*)&r0[dl];
  float4 c1 = *(const float4*)&r1[dl];
  float4 c2 = *(const float4*)&r2[dl];
  float4 c3 = *(const float4*)&r3[dl];

  float2 acc0[BB], acc1[BB];                   // pair0 = rows 0/1, pair1 = 2/3
  float2 isq0 = make_float2(0.f, 0.f), isq1 = make_float2(0.f, 0.f);
#pragma unroll
  for (int b = 0; b < BB; ++b) {
    acc0[b] = make_float2(0.f, 0.f);
    acc1[b] = make_float2(0.f, 0.f);
  }

  __syncthreads();                             // drains staging DMA (once)

#pragma unroll 1
  for (int c = 0; c < 3; ++c) {
    float4 A0 = c0, A1 = c1, A2 = c2, A3 = c3;
    if (c < 2) {                               // roll image prefetch
      const int dn = (c + 1) * 256 + dl;
      c0 = *(const float4*)&r0[dn];
      c1 = *(const float4*)&r1[dn];
      c2 = *(const float4*)&r2[dn];
      c3 = *(const float4*)&r3[dn];
    }

    isq0.x += A0.x * A0.x + A0.y * A0.y + A0.z * A0.z + A0.w * A0.w;
    isq0.y += A1.x * A1.x + A1.y * A1.y + A1.z * A1.z + A1.w * A1.w;
    isq1.x += A2.x * A2.x + A2.y * A2.y + A2.z * A2.z + A2.w * A2.w;
    isq1.y += A3.x * A3.x + A3.y * A3.y + A3.z * A3.z + A3.w * A3.w;

    const float* xb = &xs[c * 256 + dl];
#pragma unroll
    for (int b = 0; b < BB; ++b) {
      float4 xv = *(const float4*)&xb[b * DQ];  // ds_read_b128, conflict-free
      acc0[b].x += A0.x * xv.x + A0.y * xv.y + A0.z * xv.z + A0.w * xv.w;
      acc0[b].y += A1.x * xv.x + A1.y * xv.y + A1.z * xv.z + A1.w * xv.w;
      acc1[b].x += A2.x * xv.x + A2.y * xv.y + A2.z * xv.z + A2.w * xv.w;
      acc1[b].y += A3.x * xv.x + A3.y * xv.y + A3.z * xv.z + A3.w * xv.w;
    }
  }

  // one reduction per wave (verified R6/R8/R9 sequence)
  RFULL(acc0)
  RFULL(acc1)
#pragma unroll
  for (int m = 32; m >= 1; m >>= 1) {
    isq0.x += __shfl_xor(isq0.x, m, 64);
    isq0.y += __shfl_xor(isq0.y, m, 64);
    isq1.x += __shfl_xor(isq1.x, m, 64);
    isq1.y += __shfl_xor(isq1.y, m, 64);
  }

  const float sval = *svalp;
  const float at = sqrtf(1.f - sval);
  const float k1c = at / sval;                    // at / bt2
  const float k2c = (1.f - sval) / (2.f * sval);  // at^2 / (2*bt2)

  const int r = lane & 1;
  const int bb = (lane >> 2) & 15;
  if ((lane & 2) == 0) {
    float d0 = r ? acc0[0].y : acc0[0].x;
    float s0 = r ? isq0.y    : isq0.x;
    pd[((size_t)q * BB + bb) * NN + (n0 + r)] = k1c * d0 - k2c * s0;
    float d1 = r ? acc1[0].y : acc1[0].x;
    float s1 = r ? isq1.y    : isq1.x;
    pd[((size_t)q * BB + bb) * NN + (n0 + 2 + r)] = k1c * d1 - k2c * s1;
  }
}

// ---- K2: args = sum_q pd[q][b][n] -> stats + select ----
// 16 blocks x 1024 thr; thread t owns n = t, t+1024, ... (<=10 values).
__global__ __launch_bounds__(1024) void k2_select(
    const float* __restrict__ pd, int* __restrict__ cnt,
    int* __restrict__ idx, float* __restrict__ wv)
{
  __shared__ float red[16];
  __shared__ float mshared, lshared;
  const int b = blockIdx.x;
  const int t = threadIdx.x;
  const int lane = t & 63, wave = t >> 6;
  if (t == 0) cnt[b] = 0;                    // ws is poisoned 0xAA

  float a[10];
#pragma unroll
  for (int i = 0; i < 10; ++i) {
    int n = t + (i << 10);
    if (n < NN) {
      a[i] = (pd[((size_t)0 * BB + b) * NN + n] +
              pd[((size_t)1 * BB + b) * NN + n]) +
             (pd[((size_t)2 * BB + b) * NN + n] +
              pd[((size_t)3 * BB + b) * NN + n]);
    } else {
      a[i] = -INFINITY;
    }
  }

  float mx = -INFINITY;
#pragma unroll
  for (int i = 0; i < 10; ++i) mx = fmaxf(mx, a[i]);
#pragma unroll
  for (int m = 32; m >= 1; m >>= 1) mx = fmaxf(mx, __shfl_xor(mx, m, 64));
  if (lane == 0) red[wave] = mx;
  __syncthreads();
  if (wave == 0) {
    float v = (lane < 16) ? red[lane] : -INFINITY;
#pragma unroll
    for (int m = 8; m >= 1; m >>= 1) v = fmaxf(v, __shfl_xor(v, m, 64));
    if (lane == 0) mshared = v;
  }
  __syncthreads();
  mx = mshared;

  float s = 0.f;
#pragma unroll
  for (int i = 0; i < 10; ++i) s += __expf(a[i] - mx);  // exp(-inf)=0
#pragma unroll
  for (int m = 32; m >= 1; m >>= 1) s += __shfl_xor(s, m, 64);
  if (lane == 0) red[wave] = s;
  __syncthreads();
  if (wave == 0) {
    float v = (lane < 16) ? red[lane] : 0.f;
#pragma unroll
    for (int m = 8; m >= 1; m >>= 1) v += __shfl_xor(v, m, 64);
    if (lane == 0) lshared = v;
  }
  __syncthreads();
  const float invl = 1.f / lshared;

#pragma unroll
  for (int i = 0; i < 10; ++i) {
    if (a[i] > mx - SEL_CUT) {               // ~1-5 hits per row
      int k = atomicAdd(&cnt[b], 1);
      if (k < CAP) {
        idx[b * CAP + k] = t + (i << 10);
        wv[b * CAP + k] = __expf(a[i] - mx) * invl;
      }
    }
  }
}

// ---- K3: sparse mix + fused final affine -> out ----
__global__ __launch_bounds__(256) void k3_sparse(
    const float* __restrict__ images, const float* __restrict__ x,
    const float* __restrict__ svalp, const int* __restrict__ cnt,
    const int* __restrict__ idx, const float* __restrict__ wv,
    float* __restrict__ out)
{
  const int b = blockIdx.y;
  const int d0 = blockIdx.x * 1024 + (threadIdx.x << 2);
  int c = cnt[b];
  if (c > CAP) c = CAP;

  float4 acc = make_float4(0.f, 0.f, 0.f, 0.f);
  for (int j = 0; j < c; ++j) {
    int n = idx[b * CAP + j];
    float w = wv[b * CAP + j];
    float4 im = *(const float4*)&images[(size_t)n * DD + d0];
    acc.x += w * im.x; acc.y += w * im.y;
    acc.z += w * im.z; acc.w += w * im.w;
  }

  const float sval = *svalp;
  const float at = sqrtf(1.f - sval);
  const float inv_bt2 = 1.f / sval;
  float4 xv = *(const float4*)&x[b * DD + d0];
  float4 o;
  o.x = (at * acc.x - xv.x) * inv_bt2;
  o.y = (at * acc.y - xv.y) * inv_bt2;
  o.z = (at * acc.z - xv.z) * inv_bt2;
  o.w = (at * acc.w - xv.w) * inv_bt2;
  *(float4*)&out[b * DD + d0] = o;
}

extern "C" void kernel_launch(void* const* d_in, const int* in_sizes, int n_in,
                              void* d_out, int out_size, void* d_ws, size_t ws_size,
                              hipStream_t stream) {
  const float* x      = (const float*)d_in[0];
  const float* images = (const float*)d_in[1];
  const float* sval   = (const float*)d_in[2];
  float* out = (float*)d_out;
  float* ws  = (float*)d_ws;

  // ws layout (floats): pd[4*16*10000] | cnt[16]i | pad[16] |
  //                     idx[16*1024]i | wv[16*1024]   -> 2.69 MB
  float* pd  = ws;
  int*   cnt = (int*)(ws + 640000);
  int*   idx = (int*)(ws + 640032);
  float* wv  = ws + 656416;

  hipLaunchKernelGGL(k1_partial, dim3(625, 4), dim3(256), 0, stream,
                     x, images, sval, pd);
  hipLaunchKernelGGL(k2_select, dim3(16), dim3(1024), 0, stream,
                     pd, cnt, idx, wv);
  hipLaunchKernelGGL(k3_sparse, dim3(3, 16), dim3(256), 0, stream,
                     images, x, sval, cnt, idx, wv, out);
}